// Round 1
// baseline (116.079 us; speedup 1.0000x reference)
//
#include <hip/hip_runtime.h>

#define N_PIX 8192
#define C_DIM 128
#define TAU_INV_LOG2E 20.609929155556622f  // log2(e) / 0.07
#define EPS_DEN 1e-8f

typedef unsigned short u16;
typedef __attribute__((ext_vector_type(8))) short short8;
typedef __attribute__((ext_vector_type(4))) float f32x4;

__device__ __forceinline__ u16 f2bf(float f) {
    unsigned u = __float_as_uint(f);
    unsigned r = (u + 0x7fffu + ((u >> 16) & 1u)) >> 16;  // RNE
    return (u16)r;
}

// ---------------- Kernel 1: per-pixel L2-norm scales for both arrays ----------------
__global__ __launch_bounds__(256) void scale_k(const float* __restrict__ input,
                                               const float* __restrict__ target,
                                               float* __restrict__ scale_all) {
    int t = blockIdx.x * 256 + threadIdx.x;   // 0..16383
    int arr = t >> 13;                        // 0 = input, 1 = target
    int n = t & (N_PIX - 1);
    const float* src = arr ? target : input;
    int b = n >> 12, hw = n & 4095;
    const float* p = src + b * (C_DIM * 4096) + hw;
    float ss = 0.f;
#pragma unroll 8
    for (int c = 0; c < C_DIM; ++c) {
        float v = p[c * 4096];
        ss += v * v;
    }
    scale_all[t] = 1.0f / fmaxf(sqrtf(ss), 1e-12f);
}

// ------------- Kernel 2: transpose (B,C,H,W) -> (N,C) bf16 normalized rows -------------
__global__ __launch_bounds__(256) void transpose_k(const float* __restrict__ input,
                                                   const float* __restrict__ target,
                                                   const float* __restrict__ scale_all,
                                                   u16* __restrict__ ni_bf,
                                                   u16* __restrict__ nt_bf) {
    __shared__ float tile[64][65];
    int zi = blockIdx.z;
    int arr = zi >> 1, bb = zi & 1;
    const float* src = (arr ? target : input) + bb * (C_DIM * 4096);
    u16* dst = arr ? nt_bf : ni_bf;
    int hw0 = blockIdx.x * 64;
    int c0 = blockIdx.y * 64;
    int t = threadIdx.x;
    int tq = t >> 6;     // 0..3
    int tl = t & 63;
#pragma unroll
    for (int i = 0; i < 16; ++i) {
        int cl = i * 4 + tq;
        tile[cl][tl] = src[(c0 + cl) * 4096 + hw0 + tl];   // coalesced along hw
    }
    __syncthreads();
#pragma unroll
    for (int i = 0; i < 16; ++i) {
        int px = i * 4 + tq;
        int n = bb * 4096 + hw0 + px;
        float sc = scale_all[arr * N_PIX + n];
        dst[n * C_DIM + c0 + tl] = f2bf(tile[tl][px] * sc); // coalesced along c
    }
}

// ---------------- Kernel 3: fused GEMM + exp + masked column sums ----------------
// sim[a,b] = nt[a,:] . ni[b,:]; nom[b] = sum_{pt[a]==pi[b]} exp(sim/tau); den[b] = sum_a exp(sim/tau)
__global__ __launch_bounds__(256, 2) void main_k(const u16* __restrict__ ni,
                                                 const u16* __restrict__ nt,
                                                 const int* __restrict__ piseg,
                                                 const int* __restrict__ ptseg,
                                                 float* __restrict__ den,
                                                 float* __restrict__ nom) {
    __shared__ __align__(16) u16 sA[128 * 136];   // A-tile, padded stride 136 bf16
    __shared__ __align__(16) int spt[128];

    int bcb = blockIdx.x & 63;     // which 128-column block of b (input pixels)
    int as  = blockIdx.x >> 6;     // a-split index (0..7)
    int bcol0 = bcb * 128;
    int tid = threadIdx.x;
    int lane = tid & 63;
    int wave = tid >> 6;
    int wr = wave >> 1, wc = wave & 1;   // 2x2 waves over 128x128 tile
    int l15 = lane & 15, q = lane >> 4;

    // B fragments: loop-invariant, load once straight from global (L2-resident)
    short8 bfrag[4][4];
    int pil[4];
#pragma unroll
    for (int ct = 0; ct < 4; ++ct) {
        int brow = bcol0 + wc * 64 + ct * 16 + l15;
        pil[ct] = piseg[brow];
        const u16* bp = ni + brow * C_DIM + q * 8;
#pragma unroll
        for (int kc = 0; kc < 4; ++kc)
            bfrag[ct][kc] = *(const short8*)(bp + kc * 32);
    }

    float den_l[4] = {0.f, 0.f, 0.f, 0.f};
    float nom_l[4] = {0.f, 0.f, 0.f, 0.f};

    for (int it = 0; it < 8; ++it) {
        int a0 = (as * 8 + it) * 128;
        __syncthreads();   // previous iteration's sA/spt reads done
        {
            const uint4* gsrc = (const uint4*)(nt + a0 * C_DIM);  // 2048 x 16B, contiguous
#pragma unroll
            for (int i = 0; i < 8; ++i) {
                int idx = tid + i * 256;
                int r = idx >> 4, ch = idx & 15;
                *(uint4*)(&sA[r * 136 + ch * 8]) = gsrc[idx];
            }
            if (tid < 128) spt[tid] = ptseg[a0 + tid];
        }
        __syncthreads();

        f32x4 acc[4][4] = {};
#pragma unroll
        for (int kc = 0; kc < 4; ++kc) {
            short8 af[4];
#pragma unroll
            for (int rt = 0; rt < 4; ++rt) {
                int ar = wr * 64 + rt * 16 + l15;
                af[rt] = *(const short8*)(&sA[ar * 136 + kc * 32 + q * 8]);
            }
#pragma unroll
            for (int rt = 0; rt < 4; ++rt)
#pragma unroll
                for (int ct = 0; ct < 4; ++ct)
                    acc[rt][ct] = __builtin_amdgcn_mfma_f32_16x16x32_bf16(
                        af[rt], bfrag[ct][kc], acc[rt][ct], 0, 0, 0);
        }

        // epilogue: e = exp2(sim * log2e/tau); masked accumulate
#pragma unroll
        for (int rt = 0; rt < 4; ++rt) {
            int abase = wr * 64 + rt * 16 + q * 4;   // C/D layout: row = q*4 + reg
            int4 ptv = *(const int4*)(&spt[abase]);
            int pts[4] = {ptv.x, ptv.y, ptv.z, ptv.w};
#pragma unroll
            for (int ct = 0; ct < 4; ++ct) {
                f32x4 v = acc[rt][ct];
                float d = 0.f, nm = 0.f;
#pragma unroll
                for (int r = 0; r < 4; ++r) {
                    float e = __builtin_amdgcn_exp2f(v[r] * TAU_INV_LOG2E);
                    d += e;
                    nm += (pts[r] == pil[ct]) ? e : 0.f;
                }
                den_l[ct] += d;
                nom_l[ct] += nm;
            }
        }
    }

    // reduce across the 4 quads (same column, different rows), then atomics
#pragma unroll
    for (int ct = 0; ct < 4; ++ct) {
        float d = den_l[ct], nm = nom_l[ct];
        d += __shfl_xor(d, 16); d += __shfl_xor(d, 32);
        nm += __shfl_xor(nm, 16); nm += __shfl_xor(nm, 32);
        if (lane < 16) {
            int b = bcol0 + wc * 64 + ct * 16 + lane;
            atomicAdd(&den[b], d);
            atomicAdd(&nom[b], nm);
        }
    }
}

// ---------------- Kernel 4: loss = mean(-log(nom/(den+eps))) ----------------
__global__ __launch_bounds__(256) void loss_k(const float* __restrict__ den,
                                              const float* __restrict__ nom,
                                              float* __restrict__ out) {
    float s = 0.f;
    for (int i = threadIdx.x; i < N_PIX; i += 256)
        s -= __logf(nom[i] / (den[i] + EPS_DEN));
#pragma unroll
    for (int off = 32; off > 0; off >>= 1) s += __shfl_down(s, off);
    __shared__ float part[4];
    int wave = threadIdx.x >> 6;
    if ((threadIdx.x & 63) == 0) part[wave] = s;
    __syncthreads();
    if (threadIdx.x == 0)
        out[0] = (part[0] + part[1] + part[2] + part[3]) * (1.0f / N_PIX);
}

extern "C" void kernel_launch(void* const* d_in, const int* in_sizes, int n_in,
                              void* d_out, int out_size, void* d_ws, size_t ws_size,
                              hipStream_t stream) {
    const float* input  = (const float*)d_in[0];
    const float* target = (const float*)d_in[1];
    const int*   iseg   = (const int*)d_in[2];
    const int*   tseg   = (const int*)d_in[3];
    float* out = (float*)d_out;

    char* ws = (char*)d_ws;
    u16* ni_bf = (u16*)(ws);                          // 8192*128 bf16 = 2 MB
    u16* nt_bf = (u16*)(ws + (1 << 21));              // 2 MB
    float* scale_all = (float*)(ws + (1 << 22));      // 16384 f32 = 64 KB
    float* den = (float*)(ws + (1 << 22) + (64 << 10));  // 32 KB
    float* nom = (float*)(ws + (1 << 22) + (96 << 10));  // 32 KB

    hipMemsetAsync(den, 0, 64 << 10, stream);         // zero den + nom (contiguous)
    scale_k<<<64, 256, 0, stream>>>(input, target, scale_all);
    transpose_k<<<dim3(64, 2, 4), 256, 0, stream>>>(input, target, scale_all, ni_bf, nt_bf);
    main_k<<<512, 256, 0, stream>>>(ni_bf, nt_bf, iseg, tseg, den, nom);
    loss_k<<<1, 256, 0, stream>>>(den, nom, out);
}